// Round 1
// baseline (470.685 us; speedup 1.0000x reference)
//
#include <hip/hip_runtime.h>
#include <hip/hip_bf16.h>

// ---------------------------------------------------------------------------
// GraphSAGE 3-layer forward, fp32.
//   layer0: h0 = relu(segmean(x@Wl0) + x@Wr0 + b0)
//   layer1: p  = segmean(h0@Wl1) + h0@Wr1 + b1 ; h1 = relu(BN(p)) + x
//   layer2: o  = segmean(h1@Wl2) + h1@Wr2 + b2 ; out = log_softmax(o)
// Aggregation commuted through the linear map (segmean(x)@W == segmean(x@W)).
// CSR built on-device each call (deterministic up to fp sum order).
// ---------------------------------------------------------------------------

#define WS_EPS 1e-5f

// ---- CSR build -------------------------------------------------------------
__global__ __launch_bounds__(256) void k_deg(const int* __restrict__ ei,
                                             int* __restrict__ deg, int E) {
    int e = blockIdx.x * 256 + threadIdx.x;
    if (e < E) atomicAdd(&deg[ei[E + e]], 1);  // dst row
}

__global__ __launch_bounds__(1024) void k_scan(const int* __restrict__ deg,
                                               int* __restrict__ off, int n) {
    const int t = threadIdx.x;
    const int lane = t & 63;
    const int wid = t >> 6;  // 0..15
    __shared__ int swave[16];
    __shared__ int scarry;
    if (t == 0) scarry = 0;
    __syncthreads();
    for (int base = 0; base < n; base += 1024) {
        int i = base + t;
        int v = (i < n) ? deg[i] : 0;
        int x = v;
#pragma unroll
        for (int s = 1; s < 64; s <<= 1) {
            int y = __shfl_up(x, s);
            if (lane >= s) x += y;
        }
        if (lane == 63) swave[wid] = x;
        __syncthreads();
        if (wid == 0) {
            int wv = (lane < 16) ? swave[lane] : 0;
#pragma unroll
            for (int s = 1; s < 16; s <<= 1) {
                int y = __shfl_up(wv, s);
                if (lane >= s) wv += y;
            }
            if (lane < 16) swave[lane] = wv;
        }
        __syncthreads();
        int carry = scarry;
        int woff = (wid > 0) ? swave[wid - 1] : 0;
        if (i < n) off[i] = carry + woff + x - v;  // exclusive prefix
        int chunk_total = swave[15];
        __syncthreads();  // everyone done reading scarry/swave
        if (t == 0) scarry = carry + chunk_total;
        __syncthreads();
    }
    if (t == 0) off[n] = scarry;
}

__global__ __launch_bounds__(256) void k_scatter(const int* __restrict__ ei,
                                                 const int* __restrict__ off,
                                                 int* __restrict__ cur,
                                                 int* __restrict__ csr, int E) {
    int e = blockIdx.x * 256 + threadIdx.x;
    if (e < E) {
        int d = ei[E + e];
        int s = ei[e];
        int p = atomicAdd(&cur[d], 1);
        csr[off[d] + p] = s;
    }
}

// ---- GEMM: out[r][c] = sum_k X[r][k]*W[k][c] (+ AGG + bias, + relu) --------
// BM=64 rows/block, NOUT cols, K=128 in 4 chunks of 32. 256 thr, 4x(NOUT/16)
// per-thread tile. EPI: 0 plain, 1 +AGG+bias, 2 +AGG+bias+relu.
template <int NOUT, int EPI>
__global__ __launch_bounds__(256) void k_gemm(const float* __restrict__ X,
                                              const float* __restrict__ W,
                                              const float* __restrict__ AGG,
                                              const float* __restrict__ bias,
                                              float* __restrict__ out, int n) {
    constexpr int CW = NOUT / 16;  // cols per thread: 8 or 4
    const int t = threadIdx.x;
    const int tx = t & 15;   // col group
    const int ty = t >> 4;   // row group (4 rows each)
    const int row0 = blockIdx.x * 64;

    __shared__ float Xs[32][68];    // [k][r], padded (68*4B = 16B-aligned rows)
    __shared__ float Ws[32][NOUT];  // [k][c]

    float acc[4][CW];
#pragma unroll
    for (int i = 0; i < 4; ++i)
#pragma unroll
        for (int j = 0; j < CW; ++j) acc[i][j] = 0.f;

    for (int kc = 0; kc < 4; ++kc) {
        // X tile: 64 rows x 32 k = 512 float4, 2 per thread (coalesced)
#pragma unroll
        for (int u = 0; u < 2; ++u) {
            int f = t + u * 256;
            int r = f >> 3;
            int k4 = f & 7;
            int grow = row0 + r;
            float4 v = make_float4(0.f, 0.f, 0.f, 0.f);
            if (grow < n) v = *(const float4*)&X[(size_t)grow * 128 + kc * 32 + k4 * 4];
            Xs[k4 * 4 + 0][r] = v.x;
            Xs[k4 * 4 + 1][r] = v.y;
            Xs[k4 * 4 + 2][r] = v.z;
            Xs[k4 * 4 + 3][r] = v.w;
        }
        // W tile: 32 x NOUT
        constexpr int WF = 32 * NOUT / 4;
#pragma unroll
        for (int u = 0; u < WF / 256; ++u) {
            int f = t + u * 256;
            int k = f / (NOUT / 4);
            int c4 = f % (NOUT / 4);
            float4 v = *(const float4*)&W[(size_t)(kc * 32 + k) * NOUT + c4 * 4];
            *(float4*)&Ws[k][c4 * 4] = v;
        }
        __syncthreads();
#pragma unroll
        for (int k = 0; k < 32; ++k) {
            float4 a = *(const float4*)&Xs[k][ty * 4];
            float b[CW];
            *(float4*)&b[0] = *(const float4*)&Ws[k][tx * CW];
            if (CW == 8) *(float4*)&b[4] = *(const float4*)&Ws[k][tx * CW + 4];
#pragma unroll
            for (int j = 0; j < CW; ++j) {
                acc[0][j] += a.x * b[j];
                acc[1][j] += a.y * b[j];
                acc[2][j] += a.z * b[j];
                acc[3][j] += a.w * b[j];
            }
        }
        __syncthreads();
    }
#pragma unroll
    for (int i = 0; i < 4; ++i) {
        int r = row0 + ty * 4 + i;
        if (r < n) {
#pragma unroll
            for (int j4 = 0; j4 < CW; j4 += 4) {
                int c = tx * CW + j4;
                float4 v = make_float4(acc[i][j4], acc[i][j4 + 1], acc[i][j4 + 2],
                                       acc[i][j4 + 3]);
                if (EPI >= 1) {
                    float4 g = *(const float4*)&AGG[(size_t)r * NOUT + c];
                    float4 bb = *(const float4*)&bias[c];
                    v.x += g.x + bb.x;
                    v.y += g.y + bb.y;
                    v.z += g.z + bb.z;
                    v.w += g.w + bb.w;
                }
                if (EPI == 2) {
                    v.x = fmaxf(v.x, 0.f);
                    v.y = fmaxf(v.y, 0.f);
                    v.z = fmaxf(v.z, 0.f);
                    v.w = fmaxf(v.w, 0.f);
                }
                *(float4*)&out[(size_t)r * NOUT + c] = v;
            }
        }
    }
}

// ---- segment mean over CSR -------------------------------------------------
template <int D>
__global__ __launch_bounds__(256) void k_segmean(const float* __restrict__ U,
                                                 const int* __restrict__ off,
                                                 const int* __restrict__ srcs,
                                                 float* __restrict__ out, int n) {
    constexpr int PER = 256 / D;
    int node = blockIdx.x * PER + threadIdx.x / D;
    int c = threadIdx.x % D;
    if (node >= n) return;
    int beg = off[node], end = off[node + 1];
    float acc = 0.f;
    int i = beg;
    for (; i + 4 <= end; i += 4) {
        int s0 = srcs[i], s1 = srcs[i + 1], s2 = srcs[i + 2], s3 = srcs[i + 3];
        float v0 = U[(size_t)s0 * D + c];
        float v1 = U[(size_t)s1 * D + c];
        float v2 = U[(size_t)s2 * D + c];
        float v3 = U[(size_t)s3 * D + c];
        acc += v0 + v1 + v2 + v3;
    }
    for (; i < end; ++i) acc += U[(size_t)srcs[i] * D + c];
    int d = end - beg;
    out[(size_t)node * D + c] = acc / (float)(d > 1 ? d : 1);
}

// ---- BatchNorm stats (sum, sumsq per channel) ------------------------------
__global__ __launch_bounds__(256) void k_bnstats(const float* __restrict__ A,
                                                 float* __restrict__ stats, int n) {
    int c = threadIdx.x & 127;
    int h = threadIdx.x >> 7;
    int r0 = blockIdx.x * 64;
    int rend = min(r0 + 64, n);
    float s = 0.f, q = 0.f;
    for (int r = r0 + h; r < rend; r += 2) {
        float v = A[(size_t)r * 128 + c];
        s += v;
        q += v * v;
    }
    __shared__ float sh[256];
    sh[threadIdx.x] = s;
    __syncthreads();
    if (h == 0) atomicAdd(&stats[c], sh[c] + sh[c + 128]);
    __syncthreads();
    sh[threadIdx.x] = q;
    __syncthreads();
    if (h == 0) atomicAdd(&stats[128 + c], sh[c] + sh[c + 128]);
}

// ---- BN apply + relu + residual(x) ----------------------------------------
__global__ __launch_bounds__(256) void k_bnapply(const float* __restrict__ A,
                                                 const float* __restrict__ X,
                                                 const float* __restrict__ stats,
                                                 const float* __restrict__ gamma,
                                                 const float* __restrict__ beta,
                                                 float* __restrict__ H, int n) {
    int idx = blockIdx.x * 256 + threadIdx.x;
    if (idx >= n * 128) return;
    int c = idx & 127;
    float inv_n = 1.f / (float)n;
    float mu = stats[c] * inv_n;
    float var = stats[128 + c] * inv_n - mu * mu;
    float inv = rsqrtf(var + WS_EPS);
    float v = (A[idx] - mu) * inv * gamma[c] + beta[c];
    v = fmaxf(v, 0.f);
    H[idx] = v + X[idx];
}

// ---- log_softmax over 64 channels (one wave per row) -----------------------
__global__ __launch_bounds__(256) void k_logsoftmax(const float* __restrict__ A,
                                                    float* __restrict__ out, int n) {
    int r = blockIdx.x * 4 + (threadIdx.x >> 6);
    int c = threadIdx.x & 63;
    if (r >= n) return;
    float v = A[(size_t)r * 64 + c];
    float m = v;
#pragma unroll
    for (int s = 32; s; s >>= 1) m = fmaxf(m, __shfl_xor(m, s));
    float e = expf(v - m);
#pragma unroll
    for (int s = 32; s; s >>= 1) e += __shfl_xor(e, s);
    out[(size_t)r * 64 + c] = v - m - logf(e);
}

// ---------------------------------------------------------------------------
extern "C" void kernel_launch(void* const* d_in, const int* in_sizes, int n_in,
                              void* d_out, int out_size, void* d_ws, size_t ws_size,
                              hipStream_t stream) {
    const float* x     = (const float*)d_in[0];
    const int*   ei    = (const int*)d_in[1];  // [2,E], harness delivers int32
    const float* Wl0   = (const float*)d_in[2];
    const float* Wr0   = (const float*)d_in[3];
    const float* b0    = (const float*)d_in[4];
    const float* Wl1   = (const float*)d_in[5];
    const float* Wr1   = (const float*)d_in[6];
    const float* b1    = (const float*)d_in[7];
    const float* Wl2   = (const float*)d_in[8];
    const float* Wr2   = (const float*)d_in[9];
    const float* b2    = (const float*)d_in[10];
    const float* gamma = (const float*)d_in[11];
    const float* beta  = (const float*)d_in[12];

    const int n = in_sizes[0] / 128;
    const int E = in_sizes[1] / 2;

    // workspace carve-up (256B-aligned slabs)
    char* w = (char*)d_ws;
    auto alloc = [&](size_t bytes) -> void* {
        void* p = (void*)w;
        w += (bytes + 255) & ~(size_t)255;
        return p;
    };
    int*   deg   = (int*)alloc((size_t)n * 4);
    int*   cur   = (int*)alloc((size_t)n * 4);
    int*   off   = (int*)alloc(((size_t)n + 1) * 4);
    int*   csr   = (int*)alloc((size_t)E * 4);
    float* stats = (float*)alloc(256 * 4);
    float* A     = (float*)alloc((size_t)n * 128 * 4);
    float* B     = (float*)alloc((size_t)n * 128 * 4);
    float* H     = (float*)alloc((size_t)n * 128 * 4);

    hipMemsetAsync(deg, 0, (size_t)n * 4, stream);
    hipMemsetAsync(cur, 0, (size_t)n * 4, stream);
    hipMemsetAsync(stats, 0, 256 * 4, stream);

    const int eb = (E + 255) / 256;
    k_deg<<<eb, 256, 0, stream>>>(ei, deg, E);
    k_scan<<<1, 1024, 0, stream>>>(deg, off, n);
    k_scatter<<<eb, 256, 0, stream>>>(ei, off, cur, csr, E);

    const int gb = (n + 63) / 64;
    const int sm128 = (n + 1) / 2;
    const int sm64 = (n + 3) / 4;

    // layer 0: H = relu(segmean(x@Wl0) + x@Wr0 + b0)
    k_gemm<128, 0><<<gb, 256, 0, stream>>>(x, Wl0, nullptr, nullptr, A, n);
    k_segmean<128><<<sm128, 256, 0, stream>>>(A, off, csr, B, n);
    k_gemm<128, 2><<<gb, 256, 0, stream>>>(x, Wr0, B, b0, H, n);

    // layer 1: A = segmean(H@Wl1) + H@Wr1 + b1 ; H = relu(BN(A)) + x
    k_gemm<128, 0><<<gb, 256, 0, stream>>>(H, Wl1, nullptr, nullptr, A, n);
    k_segmean<128><<<sm128, 256, 0, stream>>>(A, off, csr, B, n);
    k_gemm<128, 1><<<gb, 256, 0, stream>>>(H, Wr1, B, b1, A, n);
    k_bnstats<<<gb, 256, 0, stream>>>(A, stats, n);
    const int nb = (n * 128 + 255) / 256;
    k_bnapply<<<nb, 256, 0, stream>>>(A, x, stats, gamma, beta, H, n);

    // layer 2: A = segmean(H@Wl2) + H@Wr2 + b2 ; out = log_softmax(A)
    k_gemm<64, 0><<<gb, 256, 0, stream>>>(H, Wl2, nullptr, nullptr, A, n);
    k_segmean<64><<<sm64, 256, 0, stream>>>(A, off, csr, B, n);
    k_gemm<64, 1><<<gb, 256, 0, stream>>>(H, Wr2, B, b2, A, n);
    k_logsoftmax<<<sm64, 256, 0, stream>>>(A, (float*)d_out, n);
}

// Round 2
// 307.620 us; speedup vs baseline: 1.5301x; 1.5301x over previous
//
#include <hip/hip_runtime.h>
#include <hip/hip_bf16.h>

// ---------------------------------------------------------------------------
// GraphSAGE 3-layer forward. bf16 MFMA GEMMs (f32 accum), bf16 activations,
// f32 BN/log_softmax. Aggregation commuted through the linear map.
//   layer0: H = relu(segmean(x@Wl0) + x@Wr0 + b0)           [bf16]
//   layer1: P = segmean(H@Wl1) + H@Wr1 + b1  (f32)
//           H = bf16( relu(BN(P)) + x )
//   layer2: O = segmean(H@Wl2) + H@Wr2 + b2  (f32); out = log_softmax(O)
// ---------------------------------------------------------------------------

#define WS_EPS 1e-5f

typedef unsigned short ushort_t;
typedef unsigned int uint_t;
typedef ushort_t ushort8 __attribute__((ext_vector_type(8)));
typedef short short8 __attribute__((ext_vector_type(8)));
typedef float f32x4 __attribute__((ext_vector_type(4)));

__device__ __forceinline__ float bf2f(ushort_t u) {
    uint_t x = ((uint_t)u) << 16;
    return __uint_as_float(x);
}
__device__ __forceinline__ ushort_t f2bf(float f) {
    uint_t u = __float_as_uint(f);
    u = (u + 0x7fffu + ((u >> 16) & 1u)) >> 16;  // RNE
    return (ushort_t)u;
}

// ---- CSR build -------------------------------------------------------------
__global__ __launch_bounds__(256) void k_deg(const int* __restrict__ ei,
                                             int* __restrict__ deg, int E) {
    int e = blockIdx.x * 256 + threadIdx.x;
    if (e < E) atomicAdd(&deg[ei[E + e]], 1);
}

__global__ __launch_bounds__(1024) void k_scan(const int* __restrict__ deg,
                                               int* __restrict__ off, int n) {
    const int t = threadIdx.x;
    const int lane = t & 63;
    const int wid = t >> 6;
    __shared__ int swave[16];
    __shared__ int scarry;
    if (t == 0) scarry = 0;
    __syncthreads();
    for (int base = 0; base < n; base += 1024) {
        int i = base + t;
        int v = (i < n) ? deg[i] : 0;
        int x = v;
#pragma unroll
        for (int s = 1; s < 64; s <<= 1) {
            int y = __shfl_up(x, s);
            if (lane >= s) x += y;
        }
        if (lane == 63) swave[wid] = x;
        __syncthreads();
        if (wid == 0) {
            int wv = (lane < 16) ? swave[lane] : 0;
#pragma unroll
            for (int s = 1; s < 16; s <<= 1) {
                int y = __shfl_up(wv, s);
                if (lane >= s) wv += y;
            }
            if (lane < 16) swave[lane] = wv;
        }
        __syncthreads();
        int carry = scarry;
        int woff = (wid > 0) ? swave[wid - 1] : 0;
        if (i < n) off[i] = carry + woff + x - v;
        int chunk_total = swave[15];
        __syncthreads();
        if (t == 0) scarry = carry + chunk_total;
        __syncthreads();
    }
    if (t == 0) off[n] = scarry;
}

__global__ __launch_bounds__(256) void k_scatter(const int* __restrict__ ei,
                                                 const int* __restrict__ off,
                                                 int* __restrict__ cur,
                                                 int* __restrict__ csr, int E) {
    int e = blockIdx.x * 256 + threadIdx.x;
    if (e < E) {
        int d = ei[E + e];
        int s = ei[e];
        int p = atomicAdd(&cur[d], 1);
        csr[off[d] + p] = s;
    }
}

// ---- conversions ------------------------------------------------------------
__global__ __launch_bounds__(256) void k_cvt_bf(const float* __restrict__ src,
                                                ushort_t* __restrict__ dst,
                                                int total2) {
    int i = blockIdx.x * 256 + threadIdx.x;
    if (i >= total2) return;
    float2 v = *(const float2*)&src[(size_t)i * 2];
    uint_t p = (uint_t)f2bf(v.x) | ((uint_t)f2bf(v.y) << 16);
    *(uint_t*)&dst[(size_t)i * 2] = p;
}

// Weights -> bf16, transposed: WT[c][k] = W[k][c]. Layout in `out`:
// [0)      WtL0 128x128
// [16384)  WtR0 128x128
// [32768)  WtL1 128x128
// [49152)  WtR1 128x128
// [65536)  WtL2  64x128
// [73728)  WtR2  64x128
__global__ __launch_bounds__(256) void k_prep_w(const float* __restrict__ Wl0,
                                                const float* __restrict__ Wr0,
                                                const float* __restrict__ Wl1,
                                                const float* __restrict__ Wr1,
                                                const float* __restrict__ Wl2,
                                                const float* __restrict__ Wr2,
                                                ushort_t* __restrict__ out) {
    int id = blockIdx.x * 256 + threadIdx.x;
    if (id >= 81920) return;
    const float* W;
    int rel, nout, base;
    if (id < 65536) {
        int m = id >> 14;
        rel = id & 16383;
        nout = 128;
        base = m << 14;
        W = (m == 0) ? Wl0 : (m == 1) ? Wr0 : (m == 2) ? Wl1 : Wr1;
    } else {
        int m = (id - 65536) >> 13;
        rel = (id - 65536) & 8191;
        nout = 64;
        base = 65536 + (m << 13);
        W = (m == 0) ? Wl2 : Wr2;
    }
    int c = rel >> 7;
    int k = rel & 127;
    out[base + rel] = f2bf(W[(size_t)k * nout + c]);
}

// ---- bf16 MFMA GEMM: out = X[n][128] @ W[128][NOUT] (+AGG+bias)(+relu) ------
// Block: 256 thr (4 waves), tile BM=128 x NOUT, single K=128 pass.
// EPI: 0 -> bf16 out (plain); 1 -> f32 out (+AGG+bias); 2 -> bf16 out
// (+AGG+bias, relu).
template <int NOUT, int EPI>
__global__ __launch_bounds__(256) void k_mgemm(const ushort_t* __restrict__ X,
                                               const ushort_t* __restrict__ WT,
                                               const ushort_t* __restrict__ AGG,
                                               const float* __restrict__ bias,
                                               void* __restrict__ outv, int n) {
    constexpr int BM = 128, K = 128, LDK = 136;  // +8 pad: 2-way bank alias only
    constexpr int WAVES_N = (NOUT == 128) ? 2 : 1;
    constexpr int WAVES_M = 4 / WAVES_N;
    constexpr int WM = BM / WAVES_M;   // 64 or 32
    constexpr int WN = NOUT / WAVES_N; // 64
    constexpr int FM = WM / 16;        // 4 or 2
    constexpr int FN = WN / 16;        // 4

    __shared__ ushort_t Xs[BM * LDK];
    __shared__ ushort_t Ws[NOUT * LDK];

    const int t = threadIdx.x;
    const int row0 = blockIdx.x * BM;

    // stage X tile (16B chunks, coalesced)
#pragma unroll
    for (int u = 0; u < BM * K / 8 / 256; ++u) {
        int f = u * 256 + t;
        int r = f >> 4, seg = f & 15;
        int gr = row0 + r;
        ushort8 v = (ushort8)0;
        if (gr < n) v = *(const ushort8*)&X[(size_t)gr * K + seg * 8];
        *(ushort8*)&Xs[r * LDK + seg * 8] = v;
    }
    // stage WT tile
#pragma unroll
    for (int u = 0; u < NOUT * K / 8 / 256; ++u) {
        int f = u * 256 + t;
        int r = f >> 4, seg = f & 15;
        *(ushort8*)&Ws[r * LDK + seg * 8] = *(const ushort8*)&WT[(size_t)r * K + seg * 8];
    }
    __syncthreads();

    const int lane = t & 63;
    const int wid = t >> 6;
    const int wr = wid / WAVES_N, wc = wid % WAVES_N;
    const int r16 = lane & 15, kb = lane >> 4;

    f32x4 acc[FM][FN];
#pragma unroll
    for (int i = 0; i < FM; ++i)
#pragma unroll
        for (int j = 0; j < FN; ++j) acc[i][j] = (f32x4)0.f;

#pragma unroll
    for (int ks = 0; ks < 4; ++ks) {
        short8 a[FM], b[FN];
#pragma unroll
        for (int fm = 0; fm < FM; ++fm)
            a[fm] = *(const short8*)&Xs[(wr * WM + fm * 16 + r16) * LDK + ks * 32 + kb * 8];
#pragma unroll
        for (int fn = 0; fn < FN; ++fn)
            b[fn] = *(const short8*)&Ws[(wc * WN + fn * 16 + r16) * LDK + ks * 32 + kb * 8];
#pragma unroll
        for (int fm = 0; fm < FM; ++fm)
#pragma unroll
            for (int fn = 0; fn < FN; ++fn)
                acc[fm][fn] = __builtin_amdgcn_mfma_f32_16x16x32_bf16(a[fm], b[fn], acc[fm][fn], 0, 0, 0);
    }

    // epilogue: D[row][col], row=(lane>>4)*4+r within frag, col=lane&15
#pragma unroll
    for (int fm = 0; fm < FM; ++fm) {
#pragma unroll
        for (int r = 0; r < 4; ++r) {
            int row = row0 + wr * WM + fm * 16 + kb * 4 + r;
            if (row >= n) continue;
#pragma unroll
            for (int fn = 0; fn < FN; ++fn) {
                int col = wc * WN + fn * 16 + r16;
                float v = acc[fm][fn][r];
                if (EPI >= 1) {
                    v += bf2f(AGG[(size_t)row * NOUT + col]) + bias[col];
                }
                if (EPI == 2) v = fmaxf(v, 0.f);
                if (EPI == 1)
                    ((float*)outv)[(size_t)row * NOUT + col] = v;
                else
                    ((ushort_t*)outv)[(size_t)row * NOUT + col] = f2bf(v);
            }
        }
    }
}

// ---- segment mean over CSR, bf16 in/out, f32 accum -------------------------
// 32 lanes per node; D=128 -> uint2 (4 ch) per lane, D=64 -> uint (2 ch).
template <int D>
__global__ __launch_bounds__(256) void k_segmean_bf(const ushort_t* __restrict__ U,
                                                    const int* __restrict__ off,
                                                    const int* __restrict__ srcs,
                                                    ushort_t* __restrict__ out,
                                                    int n) {
    int node = blockIdx.x * 8 + (threadIdx.x >> 5);
    int sub = threadIdx.x & 31;
    if (node >= n) return;
    int beg = off[node], end = off[node + 1];
    constexpr int CPL = D / 32;  // channels per lane: 4 or 2
    float a0 = 0.f, a1 = 0.f, a2 = 0.f, a3 = 0.f;
    int i = beg;
    for (; i + 4 <= end; i += 4) {
        int s0 = srcs[i], s1 = srcs[i + 1], s2 = srcs[i + 2], s3 = srcs[i + 3];
#pragma unroll
        for (int u = 0; u < 4; ++u) {
            int s = (u == 0) ? s0 : (u == 1) ? s1 : (u == 2) ? s2 : s3;
            if (CPL == 4) {
                uint2 v = *(const uint2*)&U[(size_t)s * D + sub * 4];
                a0 += __uint_as_float(v.x << 16);
                a1 += __uint_as_float(v.x & 0xffff0000u);
                a2 += __uint_as_float(v.y << 16);
                a3 += __uint_as_float(v.y & 0xffff0000u);
            } else {
                uint_t v = *(const uint_t*)&U[(size_t)s * D + sub * 2];
                a0 += __uint_as_float(v << 16);
                a1 += __uint_as_float(v & 0xffff0000u);
            }
        }
    }
    for (; i < end; ++i) {
        int s = srcs[i];
        if (CPL == 4) {
            uint2 v = *(const uint2*)&U[(size_t)s * D + sub * 4];
            a0 += __uint_as_float(v.x << 16);
            a1 += __uint_as_float(v.x & 0xffff0000u);
            a2 += __uint_as_float(v.y << 16);
            a3 += __uint_as_float(v.y & 0xffff0000u);
        } else {
            uint_t v = *(const uint_t*)&U[(size_t)s * D + sub * 2];
            a0 += __uint_as_float(v << 16);
            a1 += __uint_as_float(v & 0xffff0000u);
        }
    }
    int d = end - beg;
    float inv = 1.f / (float)(d > 1 ? d : 1);
    if (CPL == 4) {
        uint2 p;
        p.x = (uint_t)f2bf(a0 * inv) | ((uint_t)f2bf(a1 * inv) << 16);
        p.y = (uint_t)f2bf(a2 * inv) | ((uint_t)f2bf(a3 * inv) << 16);
        *(uint2*)&out[(size_t)node * D + sub * 4] = p;
    } else {
        uint_t p = (uint_t)f2bf(a0 * inv) | ((uint_t)f2bf(a1 * inv) << 16);
        *(uint_t*)&out[(size_t)node * D + sub * 2] = p;
    }
}

// ---- BatchNorm stats (sum, sumsq per channel) over f32 P -------------------
__global__ __launch_bounds__(256) void k_bnstats(const float* __restrict__ A,
                                                 float* __restrict__ stats, int n) {
    int c = threadIdx.x & 127;
    int h = threadIdx.x >> 7;
    int r0 = blockIdx.x * 64;
    int rend = min(r0 + 64, n);
    float s = 0.f, q = 0.f;
    for (int r = r0 + h; r < rend; r += 2) {
        float v = A[(size_t)r * 128 + c];
        s += v;
        q += v * v;
    }
    __shared__ float sh[256];
    sh[threadIdx.x] = s;
    __syncthreads();
    if (h == 0) atomicAdd(&stats[c], sh[c] + sh[c + 128]);
    __syncthreads();
    sh[threadIdx.x] = q;
    __syncthreads();
    if (h == 0) atomicAdd(&stats[128 + c], sh[c] + sh[c + 128]);
}

// ---- BN apply + relu + residual(x f32), write bf16 H -----------------------
__global__ __launch_bounds__(256) void k_bnapply(const float* __restrict__ P,
                                                 const float* __restrict__ X,
                                                 const float* __restrict__ stats,
                                                 const float* __restrict__ gamma,
                                                 const float* __restrict__ beta,
                                                 ushort_t* __restrict__ H, int n) {
    int i = blockIdx.x * 256 + threadIdx.x;  // one thread = 2 channels
    if (i >= n * 64) return;
    int nd = i >> 6;
    int c = (i & 63) << 1;
    float inv_n = 1.f / (float)n;
    float mu0 = stats[c] * inv_n, mu1 = stats[c + 1] * inv_n;
    float v0 = stats[128 + c] * inv_n - mu0 * mu0;
    float v1 = stats[128 + c + 1] * inv_n - mu1 * mu1;
    float s0 = rsqrtf(v0 + WS_EPS) * gamma[c];
    float s1 = rsqrtf(v1 + WS_EPS) * gamma[c + 1];
    float2 p = *(const float2*)&P[(size_t)nd * 128 + c];
    float2 xr = *(const float2*)&X[(size_t)nd * 128 + c];
    float h0 = fmaxf((p.x - mu0) * s0 + beta[c], 0.f) + xr.x;
    float h1 = fmaxf((p.y - mu1) * s1 + beta[c + 1], 0.f) + xr.y;
    uint_t pk = (uint_t)f2bf(h0) | ((uint_t)f2bf(h1) << 16);
    *(uint_t*)&H[(size_t)nd * 128 + c] = pk;
}

// ---- log_softmax over 64 channels (one wave per row) -----------------------
__global__ __launch_bounds__(256) void k_logsoftmax(const float* __restrict__ A,
                                                    float* __restrict__ out, int n) {
    int r = blockIdx.x * 4 + (threadIdx.x >> 6);
    int c = threadIdx.x & 63;
    if (r >= n) return;
    float v = A[(size_t)r * 64 + c];
    float m = v;
#pragma unroll
    for (int s = 32; s; s >>= 1) m = fmaxf(m, __shfl_xor(m, s));
    float e = expf(v - m);
#pragma unroll
    for (int s = 32; s; s >>= 1) e += __shfl_xor(e, s);
    out[(size_t)r * 64 + c] = v - m - logf(e);
}

// ---------------------------------------------------------------------------
extern "C" void kernel_launch(void* const* d_in, const int* in_sizes, int n_in,
                              void* d_out, int out_size, void* d_ws, size_t ws_size,
                              hipStream_t stream) {
    const float* x     = (const float*)d_in[0];
    const int*   ei    = (const int*)d_in[1];
    const float* Wl0   = (const float*)d_in[2];
    const float* Wr0   = (const float*)d_in[3];
    const float* b0    = (const float*)d_in[4];
    const float* Wl1   = (const float*)d_in[5];
    const float* Wr1   = (const float*)d_in[6];
    const float* b1    = (const float*)d_in[7];
    const float* Wl2   = (const float*)d_in[8];
    const float* Wr2   = (const float*)d_in[9];
    const float* b2    = (const float*)d_in[10];
    const float* gamma = (const float*)d_in[11];
    const float* beta  = (const float*)d_in[12];

    const int n = in_sizes[0] / 128;
    const int E = in_sizes[1] / 2;

    char* w = (char*)d_ws;
    auto alloc = [&](size_t bytes) -> void* {
        void* p = (void*)w;
        w += (bytes + 255) & ~(size_t)255;
        return p;
    };
    int*      deg   = (int*)alloc((size_t)n * 4);
    int*      cur   = (int*)alloc((size_t)n * 4);
    int*      off   = (int*)alloc(((size_t)n + 1) * 4);
    int*      csr   = (int*)alloc((size_t)E * 4);
    float*    stats = (float*)alloc(256 * 4);
    ushort_t* wts   = (ushort_t*)alloc((size_t)81920 * 2);
    ushort_t* xb    = (ushort_t*)alloc((size_t)n * 128 * 2);
    ushort_t* H     = (ushort_t*)alloc((size_t)n * 128 * 2);
    char*     slabA = (char*)alloc((size_t)n * 128 * 4);  // A bf16 | P f32 | O f32
    char*     slabB = (char*)alloc((size_t)n * 128 * 2);  // B bf16 | A64+B64 bf16

    ushort_t* WtL0 = wts;
    ushort_t* WtR0 = wts + 16384;
    ushort_t* WtL1 = wts + 32768;
    ushort_t* WtR1 = wts + 49152;
    ushort_t* WtL2 = wts + 65536;
    ushort_t* WtR2 = wts + 73728;

    ushort_t* Abf = (ushort_t*)slabA;           // [n][128] bf16
    float*    P   = (float*)slabA;              // [n][128] f32
    float*    O   = (float*)slabA;              // [n][64]  f32
    ushort_t* B   = (ushort_t*)slabB;           // [n][128] bf16
    ushort_t* A64 = (ushort_t*)slabB;           // [n][64] bf16
    ushort_t* B64 = (ushort_t*)slabB + (size_t)n * 64;

    hipMemsetAsync(deg, 0, (size_t)n * 4, stream);
    hipMemsetAsync(cur, 0, (size_t)n * 4, stream);
    hipMemsetAsync(stats, 0, 256 * 4, stream);

    const int eb = (E + 255) / 256;
    k_deg<<<eb, 256, 0, stream>>>(ei, deg, E);
    k_scan<<<1, 1024, 0, stream>>>(deg, off, n);
    k_scatter<<<eb, 256, 0, stream>>>(ei, off, cur, csr, E);

    k_cvt_bf<<<(n * 64 + 255) / 256, 256, 0, stream>>>(x, xb, n * 64);
    k_prep_w<<<320, 256, 0, stream>>>(Wl0, Wr0, Wl1, Wr1, Wl2, Wr2, wts);

    const int gb = (n + 127) / 128;
    const int smb = (n + 7) / 8;

    // layer 0
    k_mgemm<128, 0><<<gb, 256, 0, stream>>>(xb, WtL0, nullptr, nullptr, Abf, n);
    k_segmean_bf<128><<<smb, 256, 0, stream>>>(Abf, off, csr, B, n);
    k_mgemm<128, 2><<<gb, 256, 0, stream>>>(xb, WtR0, B, b0, H, n);

    // layer 1
    k_mgemm<128, 0><<<gb, 256, 0, stream>>>(H, WtL1, nullptr, nullptr, Abf, n);
    k_segmean_bf<128><<<smb, 256, 0, stream>>>(Abf, off, csr, B, n);
    k_mgemm<128, 1><<<gb, 256, 0, stream>>>(H, WtR1, B, b1, P, n);
    k_bnstats<<<(n + 63) / 64, 256, 0, stream>>>(P, stats, n);
    k_bnapply<<<(n * 64 + 255) / 256, 256, 0, stream>>>(P, x, stats, gamma, beta, H, n);

    // layer 2
    k_mgemm<64, 0><<<gb, 256, 0, stream>>>(H, WtL2, nullptr, nullptr, A64, n);
    k_segmean_bf<64><<<smb, 256, 0, stream>>>(A64, off, csr, B64, n);
    k_mgemm<64, 1><<<gb, 256, 0, stream>>>(H, WtR2, B64, b2, O, n);
    k_logsoftmax<<<(n + 3) / 4, 256, 0, stream>>>(O, (float*)d_out, n);
}

// Round 3
// 265.045 us; speedup vs baseline: 1.7759x; 1.1606x over previous
//
#include <hip/hip_runtime.h>
#include <hip/hip_bf16.h>

// ---------------------------------------------------------------------------
// GraphSAGE 3-layer forward. bf16 MFMA GEMMs (f32 accum), bf16 activations,
// f32 BN/log_softmax. Aggregation commuted through the linear map.
//   layer0: H = relu(segmean(x@Wl0) + x@Wr0 + b0)           [bf16]
//   layer1: P = segmean(H@Wl1) + H@Wr1 + b1  (f32)
//           H = bf16( relu(BN(P)) + x )
//   layer2: out = log_softmax(segmean(H@Wl2) + H@Wr2 + b2)  [fused epilogue]
// CSR prefix-sum is a hierarchical 3-kernel scan (R2's single-block scan was
// 48.5 us, latency-bound on one CU).
// ---------------------------------------------------------------------------

#define WS_EPS 1e-5f

typedef unsigned short ushort_t;
typedef unsigned int uint_t;
typedef ushort_t ushort8 __attribute__((ext_vector_type(8)));
typedef short short8 __attribute__((ext_vector_type(8)));
typedef float f32x4 __attribute__((ext_vector_type(4)));

__device__ __forceinline__ float bf2f(ushort_t u) {
    uint_t x = ((uint_t)u) << 16;
    return __uint_as_float(x);
}
__device__ __forceinline__ ushort_t f2bf(float f) {
    uint_t u = __float_as_uint(f);
    u = (u + 0x7fffu + ((u >> 16) & 1u)) >> 16;  // RNE
    return (ushort_t)u;
}

// ---- CSR build -------------------------------------------------------------
__global__ __launch_bounds__(256) void k_deg(const int* __restrict__ ei,
                                             int* __restrict__ deg, int E) {
    int e = blockIdx.x * 256 + threadIdx.x;
    if (e < E) atomicAdd(&deg[ei[E + e]], 1);
}

// hierarchical exclusive scan: 4096 elements per block
constexpr int SCHUNK = 4096;

__global__ __launch_bounds__(256) void k_scan_part(const int* __restrict__ deg,
                                                   int* __restrict__ bsum, int n) {
    int t = threadIdx.x;
    int base = blockIdx.x * SCHUNK + t * 16;
    int s = 0;
#pragma unroll
    for (int j = 0; j < 16; ++j) {
        int i = base + j;
        if (i < n) s += deg[i];
    }
#pragma unroll
    for (int d = 1; d < 64; d <<= 1) s += __shfl_xor(s, d);
    __shared__ int wt[4];
    if ((t & 63) == 0) wt[t >> 6] = s;
    __syncthreads();
    if (t == 0) bsum[blockIdx.x] = wt[0] + wt[1] + wt[2] + wt[3];
}

__global__ __launch_bounds__(64) void k_scan_bsum(const int* __restrict__ bsum,
                                                  int* __restrict__ boff,
                                                  int* __restrict__ off_n, int nb) {
    int lane = threadIdx.x;
    int carry = 0;
    for (int base = 0; base < nb; base += 64) {
        int t = base + lane;
        int v = (t < nb) ? bsum[t] : 0;
        int x = v;
#pragma unroll
        for (int d = 1; d < 64; d <<= 1) {
            int y = __shfl_up(x, d);
            if (lane >= d) x += y;
        }
        if (t < nb) boff[t] = carry + x - v;
        carry += __shfl(x, 63);
    }
    if (lane == 0) *off_n = carry;
}

__global__ __launch_bounds__(256) void k_scan_apply(const int* __restrict__ deg,
                                                    const int* __restrict__ boff,
                                                    int* __restrict__ off, int n) {
    int t = threadIdx.x;
    int lane = t & 63, wid = t >> 6;
    int base = blockIdx.x * SCHUNK + t * 16;
    int v[16];
    int s = 0;
#pragma unroll
    for (int j = 0; j < 16; ++j) {
        int i = base + j;
        v[j] = (i < n) ? deg[i] : 0;
        s += v[j];
    }
    int x = s;
#pragma unroll
    for (int d = 1; d < 64; d <<= 1) {
        int y = __shfl_up(x, d);
        if (lane >= d) x += y;
    }
    __shared__ int wtot[4];
    if (lane == 63) wtot[wid] = x;
    __syncthreads();
    int woff = 0;
    for (int wj = 0; wj < wid; ++wj) woff += wtot[wj];
    int run = boff[blockIdx.x] + woff + x - s;
#pragma unroll
    for (int j = 0; j < 16; ++j) {
        int i = base + j;
        if (i < n) off[i] = run;
        run += v[j];
    }
}

__global__ __launch_bounds__(256) void k_scatter(const int* __restrict__ ei,
                                                 const int* __restrict__ off,
                                                 int* __restrict__ cur,
                                                 int* __restrict__ csr, int E) {
    int e = blockIdx.x * 256 + threadIdx.x;
    if (e < E) {
        int d = ei[E + e];
        int s = ei[e];
        int p = atomicAdd(&cur[d], 1);
        csr[off[d] + p] = s;
    }
}

// ---- conversions ------------------------------------------------------------
__global__ __launch_bounds__(256) void k_cvt_bf(const float* __restrict__ src,
                                                ushort_t* __restrict__ dst,
                                                int total2) {
    int i = blockIdx.x * 256 + threadIdx.x;
    if (i >= total2) return;
    float2 v = *(const float2*)&src[(size_t)i * 2];
    uint_t p = (uint_t)f2bf(v.x) | ((uint_t)f2bf(v.y) << 16);
    *(uint_t*)&dst[(size_t)i * 2] = p;
}

// Weights -> bf16, transposed: WT[c][k] = W[k][c].
__global__ __launch_bounds__(256) void k_prep_w(const float* __restrict__ Wl0,
                                                const float* __restrict__ Wr0,
                                                const float* __restrict__ Wl1,
                                                const float* __restrict__ Wr1,
                                                const float* __restrict__ Wl2,
                                                const float* __restrict__ Wr2,
                                                ushort_t* __restrict__ out) {
    int id = blockIdx.x * 256 + threadIdx.x;
    if (id >= 81920) return;
    const float* W;
    int rel, nout, base;
    if (id < 65536) {
        int m = id >> 14;
        rel = id & 16383;
        nout = 128;
        base = m << 14;
        W = (m == 0) ? Wl0 : (m == 1) ? Wr0 : (m == 2) ? Wl1 : Wr1;
    } else {
        int m = (id - 65536) >> 13;
        rel = (id - 65536) & 8191;
        nout = 64;
        base = 65536 + (m << 13);
        W = (m == 0) ? Wl2 : Wr2;
    }
    int c = rel >> 7;
    int k = rel & 127;
    out[base + rel] = f2bf(W[(size_t)k * nout + c]);
}

// ---- bf16 MFMA GEMM: out = X[n][128] @ W[128][NOUT] (+AGG+bias)(+relu) ------
// EPI: 0 -> bf16 out; 1 -> f32 out (+AGG+bias); 2 -> bf16 out (+AGG+bias,relu);
//      3 -> f32 out (+AGG+bias, fused row log_softmax; NOUT==64 only).
template <int NOUT, int EPI>
__global__ __launch_bounds__(256) void k_mgemm(const ushort_t* __restrict__ X,
                                               const ushort_t* __restrict__ WT,
                                               const ushort_t* __restrict__ AGG,
                                               const float* __restrict__ bias,
                                               void* __restrict__ outv, int n) {
    constexpr int BM = 128, K = 128, LDK = 136;  // +8 pad: 2-way bank alias only
    constexpr int WAVES_N = (NOUT == 128) ? 2 : 1;
    constexpr int WAVES_M = 4 / WAVES_N;
    constexpr int WM = BM / WAVES_M;   // 64 or 32
    constexpr int WN = NOUT / WAVES_N; // 64
    constexpr int FM = WM / 16;        // 4 or 2
    constexpr int FN = WN / 16;        // 4

    __shared__ ushort_t Xs[BM * LDK];
    __shared__ ushort_t Ws[NOUT * LDK];

    const int t = threadIdx.x;
    const int row0 = blockIdx.x * BM;

#pragma unroll
    for (int u = 0; u < BM * K / 8 / 256; ++u) {
        int f = u * 256 + t;
        int r = f >> 4, seg = f & 15;
        int gr = row0 + r;
        ushort8 v = (ushort8)0;
        if (gr < n) v = *(const ushort8*)&X[(size_t)gr * K + seg * 8];
        *(ushort8*)&Xs[r * LDK + seg * 8] = v;
    }
#pragma unroll
    for (int u = 0; u < NOUT * K / 8 / 256; ++u) {
        int f = u * 256 + t;
        int r = f >> 4, seg = f & 15;
        *(ushort8*)&Ws[r * LDK + seg * 8] = *(const ushort8*)&WT[(size_t)r * K + seg * 8];
    }
    __syncthreads();

    const int lane = t & 63;
    const int wid = t >> 6;
    const int wr = wid / WAVES_N, wc = wid % WAVES_N;
    const int r16 = lane & 15, kb = lane >> 4;

    f32x4 acc[FM][FN];
#pragma unroll
    for (int i = 0; i < FM; ++i)
#pragma unroll
        for (int j = 0; j < FN; ++j) acc[i][j] = (f32x4)0.f;

#pragma unroll
    for (int ks = 0; ks < 4; ++ks) {
        short8 a[FM], b[FN];
#pragma unroll
        for (int fm = 0; fm < FM; ++fm)
            a[fm] = *(const short8*)&Xs[(wr * WM + fm * 16 + r16) * LDK + ks * 32 + kb * 8];
#pragma unroll
        for (int fn = 0; fn < FN; ++fn)
            b[fn] = *(const short8*)&Ws[(wc * WN + fn * 16 + r16) * LDK + ks * 32 + kb * 8];
#pragma unroll
        for (int fm = 0; fm < FM; ++fm)
#pragma unroll
            for (int fn = 0; fn < FN; ++fn)
                acc[fm][fn] = __builtin_amdgcn_mfma_f32_16x16x32_bf16(a[fm], b[fn], acc[fm][fn], 0, 0, 0);
    }

    if constexpr (EPI == 3) {
        // fused log_softmax over the 64 output cols (NOUT==64, WAVES_N==1):
        // a row's 64 cols live in one 16-lane group (kb fixed) x 4 fn regs.
        float* outp = (float*)outv;
#pragma unroll
        for (int fm = 0; fm < FM; ++fm) {
#pragma unroll
            for (int r = 0; r < 4; ++r) {
                int row = row0 + wr * WM + fm * 16 + kb * 4 + r;
                bool ok = (row < n);
                float vv[FN];
#pragma unroll
                for (int fn = 0; fn < FN; ++fn) {
                    int col = fn * 16 + r16;
                    vv[fn] = ok ? (acc[fm][fn][r] + bf2f(AGG[(size_t)row * NOUT + col]) + bias[col])
                                : 0.f;
                }
                float m = fmaxf(fmaxf(vv[0], vv[1]), fmaxf(vv[2], vv[3]));
#pragma unroll
                for (int d = 1; d < 16; d <<= 1) m = fmaxf(m, __shfl_xor(m, d));
                float e = expf(vv[0] - m) + expf(vv[1] - m) + expf(vv[2] - m) + expf(vv[3] - m);
#pragma unroll
                for (int d = 1; d < 16; d <<= 1) e += __shfl_xor(e, d);
                float lg = m + logf(e);
                if (ok) {
#pragma unroll
                    for (int fn = 0; fn < FN; ++fn)
                        outp[(size_t)row * NOUT + fn * 16 + r16] = vv[fn] - lg;
                }
            }
        }
    } else {
#pragma unroll
        for (int fm = 0; fm < FM; ++fm) {
#pragma unroll
            for (int r = 0; r < 4; ++r) {
                int row = row0 + wr * WM + fm * 16 + kb * 4 + r;
                if (row >= n) continue;
#pragma unroll
                for (int fn = 0; fn < FN; ++fn) {
                    int col = wc * WN + fn * 16 + r16;
                    float v = acc[fm][fn][r];
                    if (EPI >= 1) {
                        v += bf2f(AGG[(size_t)row * NOUT + col]) + bias[col];
                    }
                    if (EPI == 2) v = fmaxf(v, 0.f);
                    if (EPI == 1)
                        ((float*)outv)[(size_t)row * NOUT + col] = v;
                    else
                        ((ushort_t*)outv)[(size_t)row * NOUT + col] = f2bf(v);
                }
            }
        }
    }
}

// ---- segment mean over CSR, bf16 in/out, f32 accum -------------------------
template <int D>
__global__ __launch_bounds__(256) void k_segmean_bf(const ushort_t* __restrict__ U,
                                                    const int* __restrict__ off,
                                                    const int* __restrict__ srcs,
                                                    ushort_t* __restrict__ out,
                                                    int n) {
    int node = blockIdx.x * 8 + (threadIdx.x >> 5);
    int sub = threadIdx.x & 31;
    if (node >= n) return;
    int beg = off[node], end = off[node + 1];
    constexpr int CPL = D / 32;  // channels per lane: 4 or 2
    float a0 = 0.f, a1 = 0.f, a2 = 0.f, a3 = 0.f;
    int i = beg;
    for (; i + 4 <= end; i += 4) {
        int s0 = srcs[i], s1 = srcs[i + 1], s2 = srcs[i + 2], s3 = srcs[i + 3];
#pragma unroll
        for (int u = 0; u < 4; ++u) {
            int s = (u == 0) ? s0 : (u == 1) ? s1 : (u == 2) ? s2 : s3;
            if (CPL == 4) {
                uint2 v = *(const uint2*)&U[(size_t)s * D + sub * 4];
                a0 += __uint_as_float(v.x << 16);
                a1 += __uint_as_float(v.x & 0xffff0000u);
                a2 += __uint_as_float(v.y << 16);
                a3 += __uint_as_float(v.y & 0xffff0000u);
            } else {
                uint_t v = *(const uint_t*)&U[(size_t)s * D + sub * 2];
                a0 += __uint_as_float(v << 16);
                a1 += __uint_as_float(v & 0xffff0000u);
            }
        }
    }
    for (; i < end; ++i) {
        int s = srcs[i];
        if (CPL == 4) {
            uint2 v = *(const uint2*)&U[(size_t)s * D + sub * 4];
            a0 += __uint_as_float(v.x << 16);
            a1 += __uint_as_float(v.x & 0xffff0000u);
            a2 += __uint_as_float(v.y << 16);
            a3 += __uint_as_float(v.y & 0xffff0000u);
        } else {
            uint_t v = *(const uint_t*)&U[(size_t)s * D + sub * 2];
            a0 += __uint_as_float(v << 16);
            a1 += __uint_as_float(v & 0xffff0000u);
        }
    }
    int d = end - beg;
    float inv = 1.f / (float)(d > 1 ? d : 1);
    if (CPL == 4) {
        uint2 p;
        p.x = (uint_t)f2bf(a0 * inv) | ((uint_t)f2bf(a1 * inv) << 16);
        p.y = (uint_t)f2bf(a2 * inv) | ((uint_t)f2bf(a3 * inv) << 16);
        *(uint2*)&out[(size_t)node * D + sub * 4] = p;
    } else {
        uint_t p = (uint_t)f2bf(a0 * inv) | ((uint_t)f2bf(a1 * inv) << 16);
        *(uint_t*)&out[(size_t)node * D + sub * 2] = p;
    }
}

// ---- BatchNorm stats (sum, sumsq per channel) over f32 P -------------------
__global__ __launch_bounds__(256) void k_bnstats(const float* __restrict__ A,
                                                 float* __restrict__ stats, int n) {
    int c = threadIdx.x & 127;
    int h = threadIdx.x >> 7;
    int r0 = blockIdx.x * 64;
    int rend = min(r0 + 64, n);
    float s = 0.f, q = 0.f;
    for (int r = r0 + h; r < rend; r += 2) {
        float v = A[(size_t)r * 128 + c];
        s += v;
        q += v * v;
    }
    __shared__ float sh[256];
    sh[threadIdx.x] = s;
    __syncthreads();
    if (h == 0) atomicAdd(&stats[c], sh[c] + sh[c + 128]);
    __syncthreads();
    sh[threadIdx.x] = q;
    __syncthreads();
    if (h == 0) atomicAdd(&stats[128 + c], sh[c] + sh[c + 128]);
}

// ---- BN apply + relu + residual(x f32), write bf16 H -----------------------
__global__ __launch_bounds__(256) void k_bnapply(const float* __restrict__ P,
                                                 const float* __restrict__ X,
                                                 const float* __restrict__ stats,
                                                 const float* __restrict__ gamma,
                                                 const float* __restrict__ beta,
                                                 ushort_t* __restrict__ H, int n) {
    int i = blockIdx.x * 256 + threadIdx.x;  // one thread = 2 channels
    if (i >= n * 64) return;
    int nd = i >> 6;
    int c = (i & 63) << 1;
    float inv_n = 1.f / (float)n;
    float mu0 = stats[c] * inv_n, mu1 = stats[c + 1] * inv_n;
    float v0 = stats[128 + c] * inv_n - mu0 * mu0;
    float v1 = stats[128 + c + 1] * inv_n - mu1 * mu1;
    float s0 = rsqrtf(v0 + WS_EPS) * gamma[c];
    float s1 = rsqrtf(v1 + WS_EPS) * gamma[c + 1];
    float2 p = *(const float2*)&P[(size_t)nd * 128 + c];
    float2 xr = *(const float2*)&X[(size_t)nd * 128 + c];
    float h0 = fmaxf((p.x - mu0) * s0 + beta[c], 0.f) + xr.x;
    float h1 = fmaxf((p.y - mu1) * s1 + beta[c + 1], 0.f) + xr.y;
    uint_t pk = (uint_t)f2bf(h0) | ((uint_t)f2bf(h1) << 16);
    *(uint_t*)&H[(size_t)nd * 128 + c] = pk;
}

// ---------------------------------------------------------------------------
extern "C" void kernel_launch(void* const* d_in, const int* in_sizes, int n_in,
                              void* d_out, int out_size, void* d_ws, size_t ws_size,
                              hipStream_t stream) {
    const float* x     = (const float*)d_in[0];
    const int*   ei    = (const int*)d_in[1];
    const float* Wl0   = (const float*)d_in[2];
    const float* Wr0   = (const float*)d_in[3];
    const float* b0    = (const float*)d_in[4];
    const float* Wl1   = (const float*)d_in[5];
    const float* Wr1   = (const float*)d_in[6];
    const float* b1    = (const float*)d_in[7];
    const float* Wl2   = (const float*)d_in[8];
    const float* Wr2   = (const float*)d_in[9];
    const float* b2    = (const float*)d_in[10];
    const float* gamma = (const float*)d_in[11];
    const float* beta  = (const float*)d_in[12];

    const int n = in_sizes[0] / 128;
    const int E = in_sizes[1] / 2;
    const int nb_scan = (n + SCHUNK - 1) / SCHUNK;

    char* w = (char*)d_ws;
    auto alloc = [&](size_t bytes) -> void* {
        void* p = (void*)w;
        w += (bytes + 255) & ~(size_t)255;
        return p;
    };
    // zero-init group (contiguous -> single memset)
    int*      deg   = (int*)alloc((size_t)n * 4);
    int*      cur   = (int*)alloc((size_t)n * 4);
    float*    stats = (float*)alloc(256 * 4);
    size_t    zbytes = (size_t)((char*)w - (char*)deg);
    int*      off   = (int*)alloc(((size_t)n + 1) * 4);
    int*      csr   = (int*)alloc((size_t)E * 4);
    int*      bsum  = (int*)alloc(256 * 4);
    int*      boff  = (int*)alloc(256 * 4);
    ushort_t* wts   = (ushort_t*)alloc((size_t)81920 * 2);
    ushort_t* xb    = (ushort_t*)alloc((size_t)n * 128 * 2);
    ushort_t* H     = (ushort_t*)alloc((size_t)n * 128 * 2);
    char*     slabA = (char*)alloc((size_t)n * 128 * 4);  // Abf bf16 | P f32
    char*     slabB = (char*)alloc((size_t)n * 128 * 2);  // B bf16 | A64+B64 bf16

    ushort_t* WtL0 = wts;
    ushort_t* WtR0 = wts + 16384;
    ushort_t* WtL1 = wts + 32768;
    ushort_t* WtR1 = wts + 49152;
    ushort_t* WtL2 = wts + 65536;
    ushort_t* WtR2 = wts + 73728;

    ushort_t* Abf = (ushort_t*)slabA;
    float*    P   = (float*)slabA;
    ushort_t* B   = (ushort_t*)slabB;
    ushort_t* A64 = (ushort_t*)slabB;
    ushort_t* B64 = (ushort_t*)slabB + (size_t)n * 64;

    hipMemsetAsync(deg, 0, zbytes, stream);

    const int eb = (E + 255) / 256;
    k_deg<<<eb, 256, 0, stream>>>(ei, deg, E);
    k_scan_part<<<nb_scan, 256, 0, stream>>>(deg, bsum, n);
    k_scan_bsum<<<1, 64, 0, stream>>>(bsum, boff, off + n, nb_scan);
    k_scan_apply<<<nb_scan, 256, 0, stream>>>(deg, boff, off, n);
    k_scatter<<<eb, 256, 0, stream>>>(ei, off, cur, csr, E);

    k_cvt_bf<<<(n * 64 + 255) / 256, 256, 0, stream>>>(x, xb, n * 64);
    k_prep_w<<<320, 256, 0, stream>>>(Wl0, Wr0, Wl1, Wr1, Wl2, Wr2, wts);

    const int gb = (n + 127) / 128;
    const int smb = (n + 7) / 8;

    // layer 0
    k_mgemm<128, 0><<<gb, 256, 0, stream>>>(xb, WtL0, nullptr, nullptr, Abf, n);
    k_segmean_bf<128><<<smb, 256, 0, stream>>>(Abf, off, csr, B, n);
    k_mgemm<128, 2><<<gb, 256, 0, stream>>>(xb, WtR0, B, b0, H, n);

    // layer 1
    k_mgemm<128, 0><<<gb, 256, 0, stream>>>(H, WtL1, nullptr, nullptr, Abf, n);
    k_segmean_bf<128><<<smb, 256, 0, stream>>>(Abf, off, csr, B, n);
    k_mgemm<128, 1><<<gb, 256, 0, stream>>>(H, WtR1, B, b1, P, n);
    k_bnstats<<<(n + 63) / 64, 256, 0, stream>>>(P, stats, n);
    k_bnapply<<<(n * 64 + 255) / 256, 256, 0, stream>>>(P, x, stats, gamma, beta, H, n);

    // layer 2 (log_softmax fused into final GEMM epilogue)
    k_mgemm<64, 0><<<gb, 256, 0, stream>>>(H, WtL2, nullptr, nullptr, A64, n);
    k_segmean_bf<64><<<smb, 256, 0, stream>>>(A64, off, csr, B64, n);
    k_mgemm<64, 3><<<gb, 256, 0, stream>>>(H, WtR2, B64, b2, (float*)d_out, n);
}

// Round 4
// 233.441 us; speedup vs baseline: 2.0163x; 1.1354x over previous
//
#include <hip/hip_runtime.h>
#include <hip/hip_bf16.h>

// ---------------------------------------------------------------------------
// GraphSAGE 3-layer forward. bf16 MFMA GEMMs (f32 accum), bf16 activations.
// Layers 0/1 use DIRECT aggregation + fused dual-phase GEMM:
//   M = segmean(X);  out = X@Wr + M@Wl + b   (one kernel, 2 stage+MFMA phases)
// Layer 2 stays commuted (aggregate in 64-d, half the gather bytes):
//   A64 = H@Wl2; B64 = segmean(A64); out = log_softmax(H@Wr2 + B64 + b2)
// BN batch-stats are accumulated in the L1 GEMM epilogue (atomics).
// ---------------------------------------------------------------------------

#define WS_EPS 1e-5f

typedef unsigned short ushort_t;
typedef unsigned int uint_t;
typedef ushort_t ushort8 __attribute__((ext_vector_type(8)));
typedef short short8 __attribute__((ext_vector_type(8)));
typedef float f32x4 __attribute__((ext_vector_type(4)));

__device__ __forceinline__ float bf2f(ushort_t u) {
    return __uint_as_float(((uint_t)u) << 16);
}
__device__ __forceinline__ ushort_t f2bf(float f) {
    uint_t u = __float_as_uint(f);
    u = (u + 0x7fffu + ((u >> 16) & 1u)) >> 16;  // RNE
    return (ushort_t)u;
}

// ---- CSR build -------------------------------------------------------------
__global__ __launch_bounds__(256) void k_deg(const int* __restrict__ ei,
                                             int* __restrict__ deg, int E) {
    int e = blockIdx.x * 256 + threadIdx.x;
    if (e < E) atomicAdd(&deg[ei[E + e]], 1);
}

constexpr int SCHUNK = 4096;

__global__ __launch_bounds__(256) void k_scan_part(const int* __restrict__ deg,
                                                   int* __restrict__ bsum, int n) {
    int t = threadIdx.x;
    int base = blockIdx.x * SCHUNK + t * 16;
    int s = 0;
#pragma unroll
    for (int j = 0; j < 16; ++j) {
        int i = base + j;
        if (i < n) s += deg[i];
    }
#pragma unroll
    for (int d = 1; d < 64; d <<= 1) s += __shfl_xor(s, d);
    __shared__ int wt[4];
    if ((t & 63) == 0) wt[t >> 6] = s;
    __syncthreads();
    if (t == 0) bsum[blockIdx.x] = wt[0] + wt[1] + wt[2] + wt[3];
}

__global__ __launch_bounds__(64) void k_scan_bsum(const int* __restrict__ bsum,
                                                  int* __restrict__ boff,
                                                  int* __restrict__ off_n, int nb) {
    int lane = threadIdx.x;
    int carry = 0;
    for (int base = 0; base < nb; base += 64) {
        int t = base + lane;
        int v = (t < nb) ? bsum[t] : 0;
        int x = v;
#pragma unroll
        for (int d = 1; d < 64; d <<= 1) {
            int y = __shfl_up(x, d);
            if (lane >= d) x += y;
        }
        if (t < nb) boff[t] = carry + x - v;
        carry += __shfl(x, 63);
    }
    if (lane == 0) *off_n = carry;
}

__global__ __launch_bounds__(256) void k_scan_apply(const int* __restrict__ deg,
                                                    const int* __restrict__ boff,
                                                    int* __restrict__ off, int n) {
    int t = threadIdx.x;
    int lane = t & 63, wid = t >> 6;
    int base = blockIdx.x * SCHUNK + t * 16;
    int v[16];
    int s = 0;
#pragma unroll
    for (int j = 0; j < 16; ++j) {
        int i = base + j;
        v[j] = (i < n) ? deg[i] : 0;
        s += v[j];
    }
    int x = s;
#pragma unroll
    for (int d = 1; d < 64; d <<= 1) {
        int y = __shfl_up(x, d);
        if (lane >= d) x += y;
    }
    __shared__ int wtot[4];
    if (lane == 63) wtot[wid] = x;
    __syncthreads();
    int woff = 0;
    for (int wj = 0; wj < wid; ++wj) woff += wtot[wj];
    int run = boff[blockIdx.x] + woff + x - s;
#pragma unroll
    for (int j = 0; j < 16; ++j) {
        int i = base + j;
        if (i < n) off[i] = run;
        run += v[j];
    }
}

__global__ __launch_bounds__(256) void k_scatter(const int* __restrict__ ei,
                                                 const int* __restrict__ off,
                                                 int* __restrict__ cur,
                                                 int* __restrict__ csr, int E) {
    int e = blockIdx.x * 256 + threadIdx.x;
    if (e < E) {
        int d = ei[E + e];
        int s = ei[e];
        int p = atomicAdd(&cur[d], 1);
        csr[off[d] + p] = s;
    }
}

// ---- prep: x -> bf16 AND weights -> bf16 transposed, one launch -------------
// blocks [0, nb_cvt): convert x; blocks [nb_cvt, nb_cvt+320): weights.
__global__ __launch_bounds__(256) void k_prep(const float* __restrict__ x,
                                              ushort_t* __restrict__ xb, int total2,
                                              int nb_cvt,
                                              const float* __restrict__ Wl0,
                                              const float* __restrict__ Wr0,
                                              const float* __restrict__ Wl1,
                                              const float* __restrict__ Wr1,
                                              const float* __restrict__ Wl2,
                                              const float* __restrict__ Wr2,
                                              ushort_t* __restrict__ wts) {
    int b = blockIdx.x;
    if (b < nb_cvt) {
        int i = b * 256 + threadIdx.x;
        if (i >= total2) return;
        float2 v = *(const float2*)&x[(size_t)i * 2];
        uint_t p = (uint_t)f2bf(v.x) | ((uint_t)f2bf(v.y) << 16);
        *(uint_t*)&xb[(size_t)i * 2] = p;
        return;
    }
    int id = (b - nb_cvt) * 256 + threadIdx.x;
    if (id >= 81920) return;
    const float* W;
    int rel, nout, base;
    if (id < 65536) {
        int m = id >> 14;
        rel = id & 16383;
        nout = 128;
        base = m << 14;
        W = (m == 0) ? Wl0 : (m == 1) ? Wr0 : (m == 2) ? Wl1 : Wr1;
    } else {
        int m = (id - 65536) >> 13;
        rel = (id - 65536) & 8191;
        nout = 64;
        base = 65536 + (m << 13);
        W = (m == 0) ? Wl2 : Wr2;
    }
    int c = rel >> 7;
    int k = rel & 127;
    wts[base + rel] = f2bf(W[(size_t)k * nout + c]);
}

// ---- fused dual-phase GEMM (NOUT=128): out = X1@W1 + X2@W2 + bias ----------
// EPI: 2 -> relu, bf16 out (layer 0). 1 -> f32 out + BN stats atomics (layer1).
template <int EPI>
__global__ __launch_bounds__(256) void k_fgemm(const ushort_t* __restrict__ X1,
                                               const ushort_t* __restrict__ W1,
                                               const ushort_t* __restrict__ X2,
                                               const ushort_t* __restrict__ W2,
                                               const float* __restrict__ bias,
                                               void* __restrict__ outv,
                                               float* __restrict__ stats, int n) {
    constexpr int NOUT = 128, BM = 128, K = 128, LDK = 136;
    constexpr int WM = 64, WN = 64, FM = 4, FN = 4;

    __shared__ ushort_t Xs[BM * LDK];
    __shared__ ushort_t Ws[NOUT * LDK];

    const int t = threadIdx.x;
    const int row0 = blockIdx.x * BM;
    const int lane = t & 63;
    const int wid = t >> 6;
    const int wr = wid >> 1, wc = wid & 1;
    const int r16 = lane & 15, kb = lane >> 4;

    f32x4 acc[FM][FN];
#pragma unroll
    for (int i = 0; i < FM; ++i)
#pragma unroll
        for (int j = 0; j < FN; ++j) acc[i][j] = (f32x4)0.f;

#pragma unroll
    for (int ph = 0; ph < 2; ++ph) {
        const ushort_t* Xp = ph ? X2 : X1;
        const ushort_t* Wp = ph ? W2 : W1;
        if (ph) __syncthreads();  // all waves done reading LDS of phase 0
#pragma unroll
        for (int u = 0; u < 8; ++u) {
            int f = u * 256 + t;
            int r = f >> 4, seg = f & 15;
            int gr = row0 + r;
            ushort8 v = (ushort8)0;
            if (gr < n) v = *(const ushort8*)&Xp[(size_t)gr * K + seg * 8];
            *(ushort8*)&Xs[r * LDK + seg * 8] = v;
        }
#pragma unroll
        for (int u = 0; u < 8; ++u) {
            int f = u * 256 + t;
            int r = f >> 4, seg = f & 15;
            *(ushort8*)&Ws[r * LDK + seg * 8] = *(const ushort8*)&Wp[(size_t)r * K + seg * 8];
        }
        __syncthreads();
#pragma unroll
        for (int ks = 0; ks < 4; ++ks) {
            short8 a[FM], b[FN];
#pragma unroll
            for (int fm = 0; fm < FM; ++fm)
                a[fm] = *(const short8*)&Xs[(wr * WM + fm * 16 + r16) * LDK + ks * 32 + kb * 8];
#pragma unroll
            for (int fn = 0; fn < FN; ++fn)
                b[fn] = *(const short8*)&Ws[(wc * WN + fn * 16 + r16) * LDK + ks * 32 + kb * 8];
#pragma unroll
            for (int fm = 0; fm < FM; ++fm)
#pragma unroll
                for (int fn = 0; fn < FN; ++fn)
                    acc[fm][fn] = __builtin_amdgcn_mfma_f32_16x16x32_bf16(a[fm], b[fn], acc[fm][fn], 0, 0, 0);
        }
    }

    if constexpr (EPI == 2) {
#pragma unroll
        for (int fm = 0; fm < FM; ++fm) {
#pragma unroll
            for (int r = 0; r < 4; ++r) {
                int row = row0 + wr * WM + fm * 16 + kb * 4 + r;
                if (row >= n) continue;
#pragma unroll
                for (int fn = 0; fn < FN; ++fn) {
                    int col = wc * WN + fn * 16 + r16;
                    float v = acc[fm][fn][r] + bias[col];
                    ((ushort_t*)outv)[(size_t)row * NOUT + col] = f2bf(fmaxf(v, 0.f));
                }
            }
        }
    } else {
        float s[FN], q[FN];
#pragma unroll
        for (int fn = 0; fn < FN; ++fn) { s[fn] = 0.f; q[fn] = 0.f; }
#pragma unroll
        for (int fm = 0; fm < FM; ++fm) {
#pragma unroll
            for (int r = 0; r < 4; ++r) {
                int row = row0 + wr * WM + fm * 16 + kb * 4 + r;
                if (row >= n) continue;
#pragma unroll
                for (int fn = 0; fn < FN; ++fn) {
                    int col = wc * WN + fn * 16 + r16;
                    float v = acc[fm][fn][r] + bias[col];
                    ((float*)outv)[(size_t)row * NOUT + col] = v;
                    s[fn] += v;
                    q[fn] += v * v;
                }
            }
        }
        // reduce over kb (lane bits 4-5), then one atomic per col per wave
#pragma unroll
        for (int fn = 0; fn < FN; ++fn) {
            s[fn] += __shfl_xor(s[fn], 16);
            s[fn] += __shfl_xor(s[fn], 32);
            q[fn] += __shfl_xor(q[fn], 16);
            q[fn] += __shfl_xor(q[fn], 32);
        }
        if (kb == 0) {
#pragma unroll
            for (int fn = 0; fn < FN; ++fn) {
                int col = wc * WN + fn * 16 + r16;
                atomicAdd(&stats[col], s[fn]);
                atomicAdd(&stats[128 + col], q[fn]);
            }
        }
    }
}

// ---- single GEMM (NOUT=64) for layer 2 -------------------------------------
// EPI: 0 -> bf16 out, no AGG; 3 -> +AGG+bias, fused log_softmax, f32 out.
template <int EPI>
__global__ __launch_bounds__(256) void k_mgemm64(const ushort_t* __restrict__ X,
                                                 const ushort_t* __restrict__ WT,
                                                 const ushort_t* __restrict__ AGG,
                                                 const float* __restrict__ bias,
                                                 void* __restrict__ outv, int n) {
    constexpr int NOUT = 64, BM = 128, K = 128, LDK = 136;
    constexpr int WM = 32, WN = 64, FM = 2, FN = 4;

    __shared__ ushort_t Xs[BM * LDK];
    __shared__ ushort_t Ws[NOUT * LDK];

    const int t = threadIdx.x;
    const int row0 = blockIdx.x * BM;

#pragma unroll
    for (int u = 0; u < 8; ++u) {
        int f = u * 256 + t;
        int r = f >> 4, seg = f & 15;
        int gr = row0 + r;
        ushort8 v = (ushort8)0;
        if (gr < n) v = *(const ushort8*)&X[(size_t)gr * K + seg * 8];
        *(ushort8*)&Xs[r * LDK + seg * 8] = v;
    }
#pragma unroll
    for (int u = 0; u < 4; ++u) {
        int f = u * 256 + t;
        int r = f >> 4, seg = f & 15;
        *(ushort8*)&Ws[r * LDK + seg * 8] = *(const ushort8*)&WT[(size_t)r * K + seg * 8];
    }
    __syncthreads();

    const int lane = t & 63;
    const int wid = t >> 6;
    const int r16 = lane & 15, kb = lane >> 4;

    f32x4 acc[FM][FN];
#pragma unroll
    for (int i = 0; i < FM; ++i)
#pragma unroll
        for (int j = 0; j < FN; ++j) acc[i][j] = (f32x4)0.f;

#pragma unroll
    for (int ks = 0; ks < 4; ++ks) {
        short8 a[FM], b[FN];
#pragma unroll
        for (int fm = 0; fm < FM; ++fm)
            a[fm] = *(const short8*)&Xs[(wid * WM + fm * 16 + r16) * LDK + ks * 32 + kb * 8];
#pragma unroll
        for (int fn = 0; fn < FN; ++fn)
            b[fn] = *(const short8*)&Ws[(fn * 16 + r16) * LDK + ks * 32 + kb * 8];
#pragma unroll
        for (int fm = 0; fm < FM; ++fm)
#pragma unroll
            for (int fn = 0; fn < FN; ++fn)
                acc[fm][fn] = __builtin_amdgcn_mfma_f32_16x16x32_bf16(a[fm], b[fn], acc[fm][fn], 0, 0, 0);
    }

    if constexpr (EPI == 3) {
        float* outp = (float*)outv;
#pragma unroll
        for (int fm = 0; fm < FM; ++fm) {
#pragma unroll
            for (int r = 0; r < 4; ++r) {
                int row = row0 + wid * WM + fm * 16 + kb * 4 + r;
                bool ok = (row < n);
                float vv[FN];
#pragma unroll
                for (int fn = 0; fn < FN; ++fn) {
                    int col = fn * 16 + r16;
                    vv[fn] = ok ? (acc[fm][fn][r] + bf2f(AGG[(size_t)row * NOUT + col]) + bias[col])
                                : 0.f;
                }
                float m = fmaxf(fmaxf(vv[0], vv[1]), fmaxf(vv[2], vv[3]));
#pragma unroll
                for (int d = 1; d < 16; d <<= 1) m = fmaxf(m, __shfl_xor(m, d));
                float e = expf(vv[0] - m) + expf(vv[1] - m) + expf(vv[2] - m) + expf(vv[3] - m);
#pragma unroll
                for (int d = 1; d < 16; d <<= 1) e += __shfl_xor(e, d);
                float lg = m + logf(e);
                if (ok) {
#pragma unroll
                    for (int fn = 0; fn < FN; ++fn)
                        outp[(size_t)row * NOUT + fn * 16 + r16] = vv[fn] - lg;
                }
            }
        }
    } else {
#pragma unroll
        for (int fm = 0; fm < FM; ++fm) {
#pragma unroll
            for (int r = 0; r < 4; ++r) {
                int row = row0 + wid * WM + fm * 16 + kb * 4 + r;
                if (row >= n) continue;
#pragma unroll
                for (int fn = 0; fn < FN; ++fn) {
                    int col = fn * 16 + r16;
                    ((ushort_t*)outv)[(size_t)row * NOUT + col] = f2bf(acc[fm][fn][r]);
                }
            }
        }
    }
}

// ---- segment mean over CSR, bf16 in/out, f32 accum, 8-deep MLP --------------
template <int D>
__global__ __launch_bounds__(256) void k_segmean_bf(const ushort_t* __restrict__ U,
                                                    const int* __restrict__ off,
                                                    const int* __restrict__ srcs,
                                                    ushort_t* __restrict__ out,
                                                    int n) {
    int node = blockIdx.x * 8 + (threadIdx.x >> 5);
    int sub = threadIdx.x & 31;
    if (node >= n) return;
    int beg = off[node], end = off[node + 1];
    constexpr int CPL = D / 32;  // channels per lane: 4 or 2
    float a0 = 0.f, a1 = 0.f, a2 = 0.f, a3 = 0.f;
    int i = beg;
    for (; i + 8 <= end; i += 8) {
        int sv[8];
#pragma unroll
        for (int u = 0; u < 8; ++u) sv[u] = srcs[i + u];
#pragma unroll
        for (int u = 0; u < 8; ++u) {
            if (CPL == 4) {
                uint2 v = *(const uint2*)&U[(size_t)sv[u] * D + sub * 4];
                a0 += __uint_as_float(v.x << 16);
                a1 += __uint_as_float(v.x & 0xffff0000u);
                a2 += __uint_as_float(v.y << 16);
                a3 += __uint_as_float(v.y & 0xffff0000u);
            } else {
                uint_t v = *(const uint_t*)&U[(size_t)sv[u] * D + sub * 2];
                a0 += __uint_as_float(v << 16);
                a1 += __uint_as_float(v & 0xffff0000u);
            }
        }
    }
    for (; i + 4 <= end; i += 4) {
        int sv[4];
#pragma unroll
        for (int u = 0; u < 4; ++u) sv[u] = srcs[i + u];
#pragma unroll
        for (int u = 0; u < 4; ++u) {
            if (CPL == 4) {
                uint2 v = *(const uint2*)&U[(size_t)sv[u] * D + sub * 4];
                a0 += __uint_as_float(v.x << 16);
                a1 += __uint_as_float(v.x & 0xffff0000u);
                a2 += __uint_as_float(v.y << 16);
                a3 += __uint_as_float(v.y & 0xffff0000u);
            } else {
                uint_t v = *(const uint_t*)&U[(size_t)sv[u] * D + sub * 2];
                a0 += __uint_as_float(v << 16);
                a1 += __uint_as_float(v & 0xffff0000u);
            }
        }
    }
    for (; i < end; ++i) {
        int s = srcs[i];
        if (CPL == 4) {
            uint2 v = *(const uint2*)&U[(size_t)s * D + sub * 4];
            a0 += __uint_as_float(v.x << 16);
            a1 += __uint_as_float(v.x & 0xffff0000u);
            a2 += __uint_as_float(v.y << 16);
            a3 += __uint_as_float(v.y & 0xffff0000u);
        } else {
            uint_t v = *(const uint_t*)&U[(size_t)s * D + sub * 2];
            a0 += __uint_as_float(v << 16);
            a1 += __uint_as_float(v & 0xffff0000u);
        }
    }
    int d = end - beg;
    float inv = 1.f / (float)(d > 1 ? d : 1);
    if (CPL == 4) {
        uint2 p;
        p.x = (uint_t)f2bf(a0 * inv) | ((uint_t)f2bf(a1 * inv) << 16);
        p.y = (uint_t)f2bf(a2 * inv) | ((uint_t)f2bf(a3 * inv) << 16);
        *(uint2*)&out[(size_t)node * D + sub * 4] = p;
    } else {
        uint_t p = (uint_t)f2bf(a0 * inv) | ((uint_t)f2bf(a1 * inv) << 16);
        *(uint_t*)&out[(size_t)node * D + sub * 2] = p;
    }
}

// ---- BN apply + relu + residual(x f32), write bf16 H -----------------------
__global__ __launch_bounds__(256) void k_bnapply(const float* __restrict__ P,
                                                 const float* __restrict__ X,
                                                 const float* __restrict__ stats,
                                                 const float* __restrict__ gamma,
                                                 const float* __restrict__ beta,
                                                 ushort_t* __restrict__ H, int n) {
    int i = blockIdx.x * 256 + threadIdx.x;  // one thread = 2 channels
    if (i >= n * 64) return;
    int nd = i >> 6;
    int c = (i & 63) << 1;
    float inv_n = 1.f / (float)n;
    float mu0 = stats[c] * inv_n, mu1 = stats[c + 1] * inv_n;
    float v0 = stats[128 + c] * inv_n - mu0 * mu0;
    float v1 = stats[128 + c + 1] * inv_n - mu1 * mu1;
    float s0 = rsqrtf(v0 + WS_EPS) * gamma[c];
    float s1 = rsqrtf(v1 + WS_EPS) * gamma[c + 1];
    float2 p = *(const float2*)&P[(size_t)nd * 128 + c];
    float2 xr = *(const float2*)&X[(size_t)nd * 128 + c];
    float h0 = fmaxf((p.x - mu0) * s0 + beta[c], 0.f) + xr.x;
    float h1 = fmaxf((p.y - mu1) * s1 + beta[c + 1], 0.f) + xr.y;
    uint_t pk = (uint_t)f2bf(h0) | ((uint_t)f2bf(h1) << 16);
    *(uint_t*)&H[(size_t)nd * 128 + c] = pk;
}

// ---------------------------------------------------------------------------
extern "C" void kernel_launch(void* const* d_in, const int* in_sizes, int n_in,
                              void* d_out, int out_size, void* d_ws, size_t ws_size,
                              hipStream_t stream) {
    const float* x     = (const float*)d_in[0];
    const int*   ei    = (const int*)d_in[1];
    const float* Wl0   = (const float*)d_in[2];
    const float* Wr0   = (const float*)d_in[3];
    const float* b0    = (const float*)d_in[4];
    const float* Wl1   = (const float*)d_in[5];
    const float* Wr1   = (const float*)d_in[6];
    const float* b1    = (const float*)d_in[7];
    const float* Wl2   = (const float*)d_in[8];
    const float* Wr2   = (const float*)d_in[9];
    const float* b2    = (const float*)d_in[10];
    const float* gamma = (const float*)d_in[11];
    const float* beta  = (const float*)d_in[12];

    const int n = in_sizes[0] / 128;
    const int E = in_sizes[1] / 2;
    const int nb_scan = (n + SCHUNK - 1) / SCHUNK;

    char* w = (char*)d_ws;
    auto alloc = [&](size_t bytes) -> void* {
        void* p = (void*)w;
        w += (bytes + 255) & ~(size_t)255;
        return p;
    };
    // zero-init group (contiguous -> single memset)
    int*      deg   = (int*)alloc((size_t)n * 4);
    int*      cur   = (int*)alloc((size_t)n * 4);
    float*    stats = (float*)alloc(256 * 4);
    size_t    zbytes = (size_t)((char*)w - (char*)deg);
    int*      off   = (int*)alloc(((size_t)n + 1) * 4);
    int*      csr   = (int*)alloc((size_t)E * 4);
    int*      bsum  = (int*)alloc(256 * 4);
    int*      boff  = (int*)alloc(256 * 4);
    ushort_t* wts   = (ushort_t*)alloc((size_t)81920 * 2);
    ushort_t* xb    = (ushort_t*)alloc((size_t)n * 128 * 2);
    ushort_t* H     = (ushort_t*)alloc((size_t)n * 128 * 2);
    float*    P     = (float*)alloc((size_t)n * 128 * 4);
    ushort_t* slabB = (ushort_t*)alloc((size_t)n * 128 * 2);  // M | A64+B64

    ushort_t* WtL0 = wts;
    ushort_t* WtR0 = wts + 16384;
    ushort_t* WtL1 = wts + 32768;
    ushort_t* WtR1 = wts + 49152;
    ushort_t* WtL2 = wts + 65536;
    ushort_t* WtR2 = wts + 73728;

    ushort_t* M   = slabB;                        // [n][128] bf16 (L0/L1)
    ushort_t* A64 = slabB;                        // [n][64]  bf16 (L2)
    ushort_t* B64 = slabB + (size_t)n * 64;       // [n][64]  bf16 (L2)

    hipMemsetAsync(deg, 0, zbytes, stream);

    const int eb = (E + 255) / 256;
    k_deg<<<eb, 256, 0, stream>>>(ei, deg, E);
    k_scan_part<<<nb_scan, 256, 0, stream>>>(deg, bsum, n);
    k_scan_bsum<<<1, 64, 0, stream>>>(bsum, boff, off + n, nb_scan);
    k_scan_apply<<<nb_scan, 256, 0, stream>>>(deg, boff, off, n);
    k_scatter<<<eb, 256, 0, stream>>>(ei, off, cur, csr, E);

    const int nb_cvt = (n * 64 + 255) / 256;
    k_prep<<<nb_cvt + 320, 256, 0, stream>>>(x, xb, n * 64, nb_cvt,
                                             Wl0, Wr0, Wl1, Wr1, Wl2, Wr2, wts);

    const int gb = (n + 127) / 128;
    const int smb = (n + 7) / 8;

    // layer 0: M = segmean(xb); H = relu(xb@Wr0 + M@Wl0 + b0)
    k_segmean_bf<128><<<smb, 256, 0, stream>>>(xb, off, csr, M, n);
    k_fgemm<2><<<gb, 256, 0, stream>>>(xb, WtR0, M, WtL0, b0, H, nullptr, n);

    // layer 1: M = segmean(H); P = H@Wr1 + M@Wl1 + b1 (+BN stats);
    //          H = bf16(relu(BN(P)) + x)
    k_segmean_bf<128><<<smb, 256, 0, stream>>>(H, off, csr, M, n);
    k_fgemm<1><<<gb, 256, 0, stream>>>(H, WtR1, M, WtL1, b1, P, stats, n);
    k_bnapply<<<(n * 64 + 255) / 256, 256, 0, stream>>>(P, x, stats, gamma, beta, H, n);

    // layer 2 (commuted; log_softmax fused into final GEMM epilogue)
    k_mgemm64<0><<<gb, 256, 0, stream>>>(H, WtL2, nullptr, nullptr, A64, n);
    k_segmean_bf<64><<<smb, 256, 0, stream>>>(A64, off, csr, B64, n);
    k_mgemm64<3><<<gb, 256, 0, stream>>>(H, WtR2, B64, b2, (float*)d_out, n);
}